// Round 3
// baseline (280.989 us; speedup 1.0000x reference)
//
#include <hip/hip_runtime.h>
#include <cstdint>
#include <cstddef>

#define E 32
#define Bsz 64
#define Lsz 2048

typedef float f32x4 __attribute__((ext_vector_type(4)));
typedef __bf16 bf16x8 __attribute__((ext_vector_type(8)));
typedef short s16x8 __attribute__((ext_vector_type(8)));
typedef unsigned short u16;

__device__ inline u16 f2bf(float f) {
    union { float f; unsigned u; } x; x.f = f;
    unsigned r = x.u + 0x7FFFu + ((x.u >> 16) & 1u);
    return (u16)(r >> 16);
}
__device__ inline float bf2f(u16 h) {
    union { unsigned u; float f; } x; x.u = ((unsigned)h) << 16;
    return x.f;
}

// ---------------- PSF mask precompute: M'[i][j] = mask(i,j)/sqrt(E), bf16 ----------------
__global__ __launch_bounds__(256) void mask_kernel(u16* __restrict__ M) {
    int g = blockIdx.x * 256 + threadIdx.x;
    int i = g >> 11, j = g & 2047;
    // normalization Z = sum_{x=-10..10} exp(-x^2/8)
    float z = 0.f;
    #pragma unroll
    for (int x = -10; x <= 10; ++x) z += __expf(-0.125f * (float)(x * x));
    const float scale = 21.0f / 2048.0f;
    float si = fmaxf((i + 0.5f) * scale - 0.5f, 0.f);
    float sj = fmaxf((j + 0.5f) * scale - 0.5f, 0.f);
    int i0 = (int)si; float fi = si - (float)i0;   // si >= 0 -> trunc == floor
    int j0 = (int)sj; float fj = sj - (float)j0;
    int i0c = min(i0, 20), i1c = min(i0 + 1, 20);
    int j0c = min(j0, 20), j1c = min(j0 + 1, 20);
    int d00 = abs(i0c - j0c), d01 = abs(i0c - j1c), d10 = abs(i1c - j0c), d11 = abs(i1c - j1c);
    float t00 = __expf(-0.125f * (float)(d00 * d00));
    float t01 = __expf(-0.125f * (float)(d01 * d01));
    float t10 = __expf(-0.125f * (float)(d10 * d10));
    float t11 = __expf(-0.125f * (float)(d11 * d11));
    float m = (1.f - fi) * ((1.f - fj) * t00 + fj * t01)
            + fi * ((1.f - fj) * t10 + fj * t11);
    m = (m / z) * 0.17677669529663687f;   // * 1/sqrt(32)
    M[g] = f2bf(m);
}

// ---------------- QKV projection: x[B][E][L] fp32 -> Q,K [B][L][E] bf16, Vt [B][E][L] bf16 ----------------
__global__ __launch_bounds__(256) void qkv_kernel(const float* __restrict__ x,
        const float* __restrict__ Wqkv, const float* __restrict__ bqkv,
        u16* __restrict__ Q, u16* __restrict__ K, u16* __restrict__ Vt) {
    int g = blockIdx.x * 256 + threadIdx.x;
    int b = g >> 11, l = g & 2047;
    float xr[E];
    #pragma unroll
    for (int c = 0; c < E; ++c) xr[c] = x[((size_t)b * E + c) * Lsz + l];

    // q (rows 0..31 of Wqkv) and k (rows 32..63): row-major bf16 stores
    #pragma unroll
    for (int part = 0; part < 2; ++part) {
        u16* dst = (part == 0) ? Q : K;
        s16x8 pk[4];
        #pragma unroll
        for (int e = 0; e < E; ++e) {
            int o = part * E + e;
            float acc = bqkv[o];
            #pragma unroll
            for (int c = 0; c < E; ++c) acc += xr[c] * Wqkv[o * E + c];
            pk[e >> 3][e & 7] = (short)f2bf(acc);
        }
        s16x8* dp = (s16x8*)(dst + ((size_t)b * Lsz + l) * E);
        #pragma unroll
        for (int q8 = 0; q8 < 4; ++q8) dp[q8] = pk[q8];
    }
    // v (rows 64..95): transposed store Vt[b][e][l]
    #pragma unroll
    for (int e = 0; e < E; ++e) {
        int o = 2 * E + e;
        float acc = bqkv[o];
        #pragma unroll
        for (int c = 0; c < E; ++c) acc += xr[c] * Wqkv[o * E + c];
        Vt[((size_t)b * E + e) * Lsz + l] = f2bf(acc);
    }
}

// ---------------- Flash attention (no max-subtract; bounded masked scores) ----------------
// grid: B * (L/64) blocks, 256 threads (4 waves x 16 q-rows)
__global__ __launch_bounds__(256) void attn_kernel(const u16* __restrict__ Q,
        const u16* __restrict__ Kg, const u16* __restrict__ Vt,
        const u16* __restrict__ M, float* __restrict__ O) {
    int blk = blockIdx.x;
    int b = blk >> 5;        // 32 q-tiles per batch
    int qt = blk & 31;
    int tid = threadIdx.x;
    int wave = tid >> 6, lane = tid & 63;
    int lrow = lane & 15, kgrp = lane >> 4;
    int qbase = qt * 64 + wave * 16;

    __shared__ __align__(16) short P_lds[4][640];   // per-wave 16 rows x stride 40 halfs

    const size_t bLE = (size_t)b * Lsz * E;
    // Q A-fragment: lane holds Q[qbase+lrow][kgrp*8 .. +7]
    bf16x8 qf = *(const bf16x8*)(Q + bLE + (size_t)(qbase + lrow) * E + kgrp * 8);

    f32x4 o0 = {0.f, 0.f, 0.f, 0.f}, o1 = {0.f, 0.f, 0.f, 0.f};
    float denom[4] = {0.f, 0.f, 0.f, 0.f};
    size_t mrow[4];
    #pragma unroll
    for (int r = 0; r < 4; ++r) mrow[r] = (size_t)(qbase + kgrp * 4 + r) * Lsz;

    for (int j0 = 0; j0 < Lsz; j0 += 32) {
        // K as B-fragment: lane holds K[j0+col][kgrp*8..], col = lrow
        bf16x8 k0 = *(const bf16x8*)(Kg + bLE + (size_t)(j0 + lrow) * E + kgrp * 8);
        bf16x8 k1 = *(const bf16x8*)(Kg + bLE + (size_t)(j0 + 16 + lrow) * E + kgrp * 8);
        f32x4 zc = {0.f, 0.f, 0.f, 0.f};
        f32x4 s0 = __builtin_amdgcn_mfma_f32_16x16x32_bf16(qf, k0, zc, 0, 0, 0);
        f32x4 s1 = __builtin_amdgcn_mfma_f32_16x16x32_bf16(qf, k1, zc, 0, 0, 0);
        // C layout: col = lane&15 (j within tile), row = kgrp*4 + r
        float p0[4], p1[4];
        #pragma unroll
        for (int r = 0; r < 4; ++r) {
            float m0 = bf2f(M[mrow[r] + (size_t)(j0 + lrow)]);
            float m1 = bf2f(M[mrow[r] + (size_t)(j0 + 16 + lrow)]);
            p0[r] = __expf(s0[r] * m0);
            p1[r] = __expf(s1[r] * m1);
            denom[r] += p0[r] + p1[r];
        }
        short* pw = &P_lds[wave][0];
        #pragma unroll
        for (int r = 0; r < 4; ++r) {
            pw[(kgrp * 4 + r) * 40 + lrow]      = (short)f2bf(p0[r]);
            pw[(kgrp * 4 + r) * 40 + 16 + lrow] = (short)f2bf(p1[r]);
        }
        __syncthreads();
        // P A-fragment: row = lrow, k(j) = kgrp*8..+7
        bf16x8 pf = *(const bf16x8*)(&P_lds[wave][0] + lrow * 40 + kgrp * 8);
        // V B-fragment from Vt[b][e][l]: col(e) = lrow, k(j) = j0 + kgrp*8..
        bf16x8 v0 = *(const bf16x8*)(Vt + bLE + (size_t)lrow * Lsz + j0 + kgrp * 8);
        bf16x8 v1 = *(const bf16x8*)(Vt + bLE + (size_t)(16 + lrow) * Lsz + j0 + kgrp * 8);
        o0 = __builtin_amdgcn_mfma_f32_16x16x32_bf16(pf, v0, o0, 0, 0, 0);
        o1 = __builtin_amdgcn_mfma_f32_16x16x32_bf16(pf, v1, o1, 0, 0, 0);
        __syncthreads();
    }
    // denominator: reduce across the 16 lanes of each row-group
    #pragma unroll
    for (int r = 0; r < 4; ++r) {
        #pragma unroll
        for (int mk = 1; mk <= 8; mk <<= 1) denom[r] += __shfl_xor(denom[r], mk);
    }
    #pragma unroll
    for (int r = 0; r < 4; ++r) {
        size_t row = (size_t)(qbase + kgrp * 4 + r);
        float inv = 1.0f / denom[r];
        O[bLE + row * E + lrow]      = o0[r] * inv;
        O[bLE + row * E + 16 + lrow] = o1[r] * inv;
    }
}

// ---------------- Output projection: O[B][L][E] fp32 -> y[B][E][L] fp32 ----------------
__global__ __launch_bounds__(256) void oproj_kernel(const float* __restrict__ O,
        const float* __restrict__ Wout, const float* __restrict__ bout,
        float* __restrict__ y) {
    int g = blockIdx.x * 256 + threadIdx.x;
    int b = g >> 11, l = g & 2047;
    float orow[E];
    const float* src = O + ((size_t)b * Lsz + l) * E;
    #pragma unroll
    for (int e = 0; e < E; e += 4) {
        f32x4 t = *(const f32x4*)(src + e);
        orow[e] = t[0]; orow[e + 1] = t[1]; orow[e + 2] = t[2]; orow[e + 3] = t[3];
    }
    #pragma unroll
    for (int c = 0; c < E; ++c) {
        float acc = bout[c];
        #pragma unroll
        for (int e = 0; e < E; ++e) acc += orow[e] * Wout[c * E + e];
        y[((size_t)b * E + c) * Lsz + l] = acc;
    }
}

extern "C" void kernel_launch(void* const* d_in, const int* in_sizes, int n_in,
                              void* d_out, int out_size, void* d_ws, size_t ws_size,
                              hipStream_t stream) {
    const float* x    = (const float*)d_in[0];
    const float* Wqkv = (const float*)d_in[1];
    const float* bqkv = (const float*)d_in[2];
    const float* Wout = (const float*)d_in[3];
    const float* bout = (const float*)d_in[4];
    float* y = (float*)d_out;

    char* ws = (char*)d_ws;
    const size_t szQ = (size_t)Bsz * Lsz * E * sizeof(u16);   // 8.39 MB
    const size_t szM = (size_t)Lsz * Lsz * sizeof(u16);       // 8.39 MB
    u16* Q   = (u16*)(ws);
    u16* K   = (u16*)(ws + szQ);
    u16* Vt  = (u16*)(ws + 2 * szQ);
    u16* M   = (u16*)(ws + 3 * szQ);
    float* O = (float*)(ws + 3 * szQ + szM);                  // 16.78 MB fp32

    hipLaunchKernelGGL(mask_kernel, dim3((Lsz * Lsz) / 256), dim3(256), 0, stream, M);
    hipLaunchKernelGGL(qkv_kernel, dim3((Bsz * Lsz) / 256), dim3(256), 0, stream,
                       x, Wqkv, bqkv, Q, K, Vt);
    hipLaunchKernelGGL(attn_kernel, dim3(Bsz * (Lsz / 64)), dim3(256), 0, stream,
                       Q, K, Vt, M, O);
    hipLaunchKernelGGL(oproj_kernel, dim3((Bsz * Lsz) / 256), dim3(256), 0, stream,
                       O, Wout, bout, y);
}